// Round 7
// baseline (718.135 us; speedup 1.0000x reference)
//
#include <hip/hip_runtime.h>
#include <math.h>

#define NB 8192
#define NE 8
#define F1 1024
#define F2 2048
#define NC 100
#define NCP 112
#define TM 128
#define BK 32
#define NKT (F1 / BK)    // 32
#define NCC (F2 / 128)   // 16
#define MAXTY 72

#define WS_CUR   17
#define WS_TYE   32
#define WS_TYR   104
#define WS_TYN   176
#define WS_ROWS  256

#define OFF_XH  ((size_t)65536)
#define SZ_X    ((size_t)NB * F1)
#define OFF_W1H (OFF_XH + 4 * SZ_X)
#define SZ_W1   ((size_t)NE * F2 * F1)
#define OFF_W2H (OFF_W1H + 4 * SZ_W1)
#define SZ_W2   ((size_t)NE * NCP * F2)

typedef float f32x4 __attribute__((ext_vector_type(4)));
typedef short s16x8 __attribute__((ext_vector_type(8)));
typedef unsigned short u16x8 __attribute__((ext_vector_type(8)));
typedef unsigned short u16x4 __attribute__((ext_vector_type(4)));

__device__ __forceinline__ unsigned short bf_hi(float f) {
    unsigned u = __float_as_uint(f);
    return (unsigned short)((u + 0x7FFFu + ((u >> 16) & 1u)) >> 16);  // RNE
}
__device__ __forceinline__ float bf_up(unsigned short h) {
    return __uint_as_float(((unsigned)h) << 16);
}

typedef const __attribute__((address_space(1))) unsigned cgu;
typedef __attribute__((address_space(3))) unsigned ldu;
__device__ __forceinline__ void gl16(const void* g, void* l) {
    __builtin_amdgcn_global_load_lds((cgu*)g, (ldu*)l, 16, 0, 0);
}

// -------- planning: ballot histogram + ty table --------
__global__ __launch_bounds__(512) void k_plan(const int* __restrict__ dom, int* ws) {
    __shared__ int wh[8][8];
    const int tid = threadIdx.x, wave = tid >> 6, lane = tid & 63;
    int cnt[NE];
#pragma unroll
    for (int e = 0; e < NE; ++e) cnt[e] = 0;
    for (int i = tid; i < NB / 4; i += 512) {
        int4 d = ((const int4*)dom)[i];
        int v[4] = {d.x, d.y, d.z, d.w};
#pragma unroll
        for (int t = 0; t < 4; ++t)
#pragma unroll
            for (int e = 0; e < NE; ++e)
                cnt[e] += (int)__popcll(__ballot(v[t] == e));
    }
    if (lane == 0)
#pragma unroll
        for (int e = 0; e < NE; ++e) wh[wave][e] = cnt[e];
    __syncthreads();
    if (tid == 0) {
        int c[NE], off = 0, ty = 0;
        for (int e = 0; e < NE; ++e) {
            c[e] = 0;
            for (int w = 0; w < 8; ++w) c[e] += wh[w][e];
        }
        for (int e = 0; e < NE; ++e) {
            ws[WS_CUR + e] = off;
            int nt = (c[e] + TM - 1) / TM;
            for (int t = 0; t < nt; ++t) {
                ws[WS_TYE + ty] = e;
                ws[WS_TYR + ty] = off + t * TM;
                ws[WS_TYN + ty] = min(TM, c[e] - t * TM);
                ++ty;
            }
            off += c[e];
        }
        for (; ty < MAXTY; ++ty) ws[WS_TYN + ty] = 0;
    }
}

__global__ __launch_bounds__(256) void k_scatter(const int* __restrict__ dom, int* ws) {
    __shared__ int lh[NE], base[NE];
    const int tid = threadIdx.x;
    if (tid < NE) lh[tid] = 0;
    __syncthreads();
    const int b = blockIdx.x * 256 + tid;
    const int e = dom[b];
    const int r = atomicAdd(&lh[e], 1);
    __syncthreads();
    if (tid < NE) base[tid] = atomicAdd(&ws[WS_CUR + tid], lh[tid]);
    __syncthreads();
    ws[WS_ROWS + base[e] + r] = b;
}

// -------- fused pre-pass: x split | W1 transpose+split | W2 transpose+split ----
__global__ __launch_bounds__(256) void k_prep(
    const float* __restrict__ x, const float* __restrict__ W1,
    const float* __restrict__ W2, unsigned short* __restrict__ xh,
    unsigned short* __restrict__ w1h, unsigned short* __restrict__ w2h)
{
    __shared__ float t[64 * 101];
    const int bx = blockIdx.x;
    if (bx < 2048) {
        unsigned short* xl = xh + SZ_X;
#pragma unroll
        for (int q = 0; q < 4; ++q) {
            size_t i = (size_t)bx * 1024 + q * 256 + threadIdx.x;
            float4 v = *(const float4*)(x + i * 4);
            u16x4 h, l;
            float f[4] = {v.x, v.y, v.z, v.w};
#pragma unroll
            for (int c = 0; c < 4; ++c) {
                unsigned short hh = bf_hi(f[c]);
                h[c] = hh;
                l[c] = bf_hi(f[c] - bf_up(hh));
            }
            *(u16x4*)(xh + i * 4) = h;
            *(u16x4*)(xl + i * 4) = l;
        }
    } else if (bx < 2048 + 4096) {
        unsigned short* w1l = w1h + SZ_W1;
        const int tt = bx - 2048;
        const int e = tt >> 9, rem = tt & 511;
        const int k0 = (rem >> 5) * 64, n0 = (rem & 31) * 64;
        const float* src = W1 + ((size_t)e * F1 + k0) * F2 + n0;
#pragma unroll
        for (int i = 0; i < 4; ++i) {
            int u = threadIdx.x + 256 * i;
            int k = u >> 4, n4 = (u & 15) * 4;
            float4 v = *(const float4*)(src + (size_t)k * F2 + n4);
            t[k * 65 + n4] = v.x; t[k * 65 + n4 + 1] = v.y;
            t[k * 65 + n4 + 2] = v.z; t[k * 65 + n4 + 3] = v.w;
        }
        __syncthreads();
#pragma unroll
        for (int i = 0; i < 2; ++i) {
            int u = threadIdx.x + 256 * i;
            int n = u >> 3, kg = u & 7;
            u16x8 hv, lv;
#pragma unroll
            for (int j = 0; j < 8; ++j) {
                float v = t[(kg * 8 + j) * 65 + n];
                unsigned short hh = bf_hi(v);
                hv[j] = hh;
                lv[j] = bf_hi(v - bf_up(hh));
            }
            size_t dst = ((size_t)e * F2 + n0 + n) * F1 + k0 + kg * 8;
            *(u16x8*)(w1h + dst) = hv;
            *(u16x8*)(w1l + dst) = lv;
        }
    } else {
        unsigned short* w2l = w2h + SZ_W2;
        const int tt = bx - 6144;
        const int e = tt >> 5, k0 = (tt & 31) * 64;
        const float* src = W2 + ((size_t)e * F2 + k0) * NC;
        for (int u = threadIdx.x; u < 64 * NC; u += 256) {
            int k = u / NC, c = u - k * NC;
            t[k * 101 + c] = src[u];
        }
        __syncthreads();
#pragma unroll
        for (int i = 0; i < 4; ++i) {
            int u = threadIdx.x + 256 * i;
            if (u < NCP * 8) {
                int c = u >> 3, kg = u & 7;
                u16x8 hv, lv;
#pragma unroll
                for (int j = 0; j < 8; ++j) {
                    float v = (c < NC) ? t[(kg * 8 + j) * 101 + c] : 0.f;
                    unsigned short hh = bf_hi(v);
                    hv[j] = hh;
                    lv[j] = bf_hi(v - bf_up(hh));
                }
                size_t dst = ((size_t)e * NCP + c) * F2 + k0 + kg * 8;
                *(u16x8*)(w2h + dst) = hv;
                *(u16x8*)(w2l + dst) = lv;
            }
        }
    }
}

// -------- fused grouped GEMM: 256 thr, 128x128, BK=32, 33KB LDS, 4 blk/CU ----
// Subtile LDS bijection (verified 0-conflict in r5): unit u(r,s) = (r>>4)*64 +
// s*16 + (r&15); frag read = contiguous 1KB per wave. Planes (ushorts):
// Ah [0,4096) Al [4096,8192) Bh [8192,12288) Bl [12288,16384).
__global__ __launch_bounds__(256, 4) void k_g1(
    const int* __restrict__ ws, const unsigned short* __restrict__ xh,
    const unsigned short* __restrict__ w1h, const unsigned short* __restrict__ w2h,
    const float* __restrict__ b1, float* __restrict__ out)
{
    __shared__ __align__(16) unsigned short sb[16384];   // 32 KB
    __shared__ int rows[TM];
    const int tid = threadIdx.x;
    const int cc = blockIdx.x;
    const int ty = blockIdx.y;

    const int nr = ws[WS_TYN + ty];
    if (nr <= 0) return;
    const int e = ws[WS_TYE + ty];
    const int rbase = ws[WS_TYR + ty];
    if (tid < TM) rows[tid] = ws[WS_ROWS + rbase + min(tid, nr - 1)];
    __syncthreads();

    const int wave = tid >> 6, lane = tid & 63;
    const int wm = wave >> 1, wn = wave & 1;
    const int lg = lane >> 4, ln = lane & 15;

    // phase-A staging: thread -> units u = tid, tid+256; u -> (r,s)
    const unsigned short* pA[2];
    const unsigned short* pB[2];
#pragma unroll
    for (int i = 0; i < 2; ++i) {
        int u = tid + 256 * i;
        int r = ((u >> 6) << 4) + (u & 15), s = (u >> 4) & 3;
        pA[i] = xh + (size_t)rows[r] * F1 + s * 8;
        pB[i] = w1h + ((size_t)e * F2 + cc * 128 + r) * F1 + s * 8;
    }
    const int ldst0 = tid * 8, ldst1 = ldst0 + 2048;

    float bias[4];
#pragma unroll
    for (int nf = 0; nf < 4; ++nf)
        bias[nf] = b1[e * F2 + cc * 128 + wn * 64 + nf * 16 + ln];

    int aoff[4], boff[4];
#pragma unroll
    for (int m = 0; m < 4; ++m) aoff[m] = ((wm * 4 + m) * 64 + lg * 16 + ln) * 8;
#pragma unroll
    for (int n = 0; n < 4; ++n) boff[n] = 8192 + ((wn * 4 + n) * 64 + lg * 16 + ln) * 8;

    f32x4 acc[4][4];
#pragma unroll
    for (int m = 0; m < 4; ++m)
#pragma unroll
        for (int n = 0; n < 4; ++n) acc[m][n] = (f32x4){0.f, 0.f, 0.f, 0.f};

    for (int kt = 0; kt < NKT; ++kt) {
        const int ko = kt * BK;
        gl16(pA[0] + ko,          &sb[ldst0]);
        gl16(pA[1] + ko,          &sb[ldst1]);
        gl16(pA[0] + SZ_X + ko,   &sb[4096 + ldst0]);
        gl16(pA[1] + SZ_X + ko,   &sb[4096 + ldst1]);
        gl16(pB[0] + ko,          &sb[8192 + ldst0]);
        gl16(pB[1] + ko,          &sb[8192 + ldst1]);
        gl16(pB[0] + SZ_W1 + ko,  &sb[12288 + ldst0]);
        gl16(pB[1] + SZ_W1 + ko,  &sb[12288 + ldst1]);
        __syncthreads();            // drains vmcnt; 4 co-resident blocks overlap
        s16x8 ah[4], al[4];
#pragma unroll
        for (int m = 0; m < 4; ++m) {
            ah[m] = *(const s16x8*)&sb[aoff[m]];
            al[m] = *(const s16x8*)&sb[4096 + aoff[m]];
        }
#pragma unroll
        for (int n = 0; n < 4; ++n) {
            s16x8 bh = *(const s16x8*)&sb[boff[n]];
            s16x8 bl = *(const s16x8*)&sb[4096 + boff[n]];
#pragma unroll
            for (int m = 0; m < 4; ++m) {
                acc[m][n] = __builtin_amdgcn_mfma_f32_16x16x32_bf16(ah[m], bh, acc[m][n], 0, 0, 0);
                acc[m][n] = __builtin_amdgcn_mfma_f32_16x16x32_bf16(al[m], bh, acc[m][n], 0, 0, 0);
                acc[m][n] = __builtin_amdgcn_mfma_f32_16x16x32_bf16(ah[m], bl, acc[m][n], 0, 0, 0);
            }
        }
        __syncthreads();
    }

    // ---- phase B: 4 k2-slices of 32. Same subtile bijection. Planes:
    // Hh [0,4096) Hl [4096,8192) W2h [8192,11776) W2l [11776,15360)
    f32x4 acc2[2][7];
#pragma unroll
    for (int mf = 0; mf < 2; ++mf)
#pragma unroll
        for (int cf = 0; cf < 7; ++cf) acc2[mf][cf] = (f32x4){0.f, 0.f, 0.f, 0.f};

    for (int sl = 0; sl < 4; ++sl) {
        if (wn == (sl >> 1)) {      // writer waves for this 32-col slice
#pragma unroll
            for (int m = 0; m < 4; ++m)
#pragma unroll
                for (int nfh = 0; nfh < 2; ++nfh) {
                    const int nf = (sl & 1) * 2 + nfh;
                    const float bb = bias[nf];
                    const int k2 = nfh * 16 + ln;        // 0..31 within slice
                    const int su = (k2 >> 3) * 16;       // slot*16
#pragma unroll
                    for (int reg = 0; reg < 4; ++reg) {
                        const int r = wm * 64 + m * 16 + lg * 4 + reg;
                        float v = fmaxf(acc[m][nf][reg] + bb, 0.f);
                        unsigned short hh = bf_hi(v);
                        int off = (((r >> 4) << 6) + su + (r & 15)) * 8 + (k2 & 7);
                        sb[off] = hh;
                        sb[4096 + off] = bf_hi(v - bf_up(hh));
                    }
                }
        }
        // stage W2t slice: 448 16B units
        {
            int u = tid;
            int c = ((u >> 6) << 4) + (u & 15), s = (u >> 4) & 3;
            const unsigned short* src =
                w2h + ((size_t)e * NCP + c) * F2 + cc * 128 + sl * 32 + s * 8;
            gl16(src,         &sb[8192 + u * 8]);
            gl16(src + SZ_W2, &sb[11776 + u * 8]);
            if (tid < 192) {
                u = tid + 256;
                c = ((u >> 6) << 4) + (u & 15); s = (u >> 4) & 3;
                src = w2h + ((size_t)e * NCP + c) * F2 + cc * 128 + sl * 32 + s * 8;
                gl16(src,         &sb[8192 + u * 8]);
                gl16(src + SZ_W2, &sb[11776 + u * 8]);
            }
        }
        __syncthreads();
        s16x8 hh[2], hl[2];
#pragma unroll
        for (int mf = 0; mf < 2; ++mf) {
            int off = ((wave * 2 + mf) * 64 + lg * 16 + ln) * 8;
            hh[mf] = *(const s16x8*)&sb[off];
            hl[mf] = *(const s16x8*)&sb[4096 + off];
        }
#pragma unroll
        for (int cf = 0; cf < 7; ++cf) {
            int off = 8192 + (cf * 64 + lg * 16 + ln) * 8;
            s16x8 wh = *(const s16x8*)&sb[off];
            s16x8 wl = *(const s16x8*)&sb[3584 + off];
#pragma unroll
            for (int mf = 0; mf < 2; ++mf) {
                acc2[mf][cf] = __builtin_amdgcn_mfma_f32_16x16x32_bf16(hh[mf], wh, acc2[mf][cf], 0, 0, 0);
                acc2[mf][cf] = __builtin_amdgcn_mfma_f32_16x16x32_bf16(hl[mf], wh, acc2[mf][cf], 0, 0, 0);
                acc2[mf][cf] = __builtin_amdgcn_mfma_f32_16x16x32_bf16(hh[mf], wl, acc2[mf][cf], 0, 0, 0);
            }
        }
        __syncthreads();
    }

#pragma unroll
    for (int mf = 0; mf < 2; ++mf)
#pragma unroll
        for (int cf = 0; cf < 7; ++cf) {
            int c = cf * 16 + ln;
            if (c < NC) {
#pragma unroll
                for (int reg = 0; reg < 4; ++reg) {
                    int row = wave * 32 + mf * 16 + lg * 4 + reg;
                    if (row < nr)
                        atomicAdd(out + (size_t)rows[row] * NC + c, acc2[mf][cf][reg]);
                }
            }
        }
}

__global__ void k_sm(const int* __restrict__ dom, const float* __restrict__ b2,
                     float* __restrict__ out)
{
    const int row = blockIdx.x * 4 + (threadIdx.x >> 6);
    const int lane = threadIdx.x & 63;
    const int e = dom[row];
    float* base = out + (size_t)row * NC;
    float v0 = base[lane] + b2[e * NC + lane];
    float v1 = -1e30f;
    if (lane + 64 < NC) v1 = base[lane + 64] + b2[e * NC + lane + 64];
    float m = fmaxf(v0, v1);
#pragma unroll
    for (int s = 1; s < 64; s <<= 1) m = fmaxf(m, __shfl_xor(m, s));
    float p0 = expf(v0 - m);
    float p1 = (lane + 64 < NC) ? expf(v1 - m) : 0.f;
    float sum = p0 + p1;
#pragma unroll
    for (int s = 1; s < 64; s <<= 1) sum += __shfl_xor(sum, s);
    float inv = 1.f / sum;
    base[lane] = p0 * inv;
    if (lane + 64 < NC) base[lane + 64] = p1 * inv;
}

extern "C" void kernel_launch(void* const* d_in, const int* in_sizes, int n_in,
                              void* d_out, int out_size, void* d_ws, size_t ws_size,
                              hipStream_t stream)
{
    const int*   dom = (const int*)d_in[0];
    const float* x   = (const float*)d_in[1];
    const float* W1  = (const float*)d_in[2];
    const float* b1  = (const float*)d_in[3];
    const float* W2  = (const float*)d_in[4];
    const float* b2  = (const float*)d_in[5];
    float*       out = (float*)d_out;
    int*         ws  = (int*)d_ws;

    unsigned short* xh  = (unsigned short*)((char*)d_ws + OFF_XH);
    unsigned short* w1h = (unsigned short*)((char*)d_ws + OFF_W1H);
    unsigned short* w2h = (unsigned short*)((char*)d_ws + OFF_W2H);

    hipMemsetAsync(out, 0, (size_t)NB * NC * sizeof(float), stream);
    hipLaunchKernelGGL(k_plan,    dim3(1), dim3(512), 0, stream, dom, ws);
    hipLaunchKernelGGL(k_scatter, dim3(NB / 256), dim3(256), 0, stream, dom, ws);
    hipLaunchKernelGGL(k_prep,    dim3(2048 + 4096 + 256), dim3(256), 0, stream,
                       x, W1, W2, xh, w1h, w2h);
    hipLaunchKernelGGL(k_g1,      dim3(NCC, MAXTY), dim3(256), 0, stream,
                       ws, xh, w1h, w2h, b1, out);
    hipLaunchKernelGGL(k_sm,      dim3(NB / 4), dim3(256), 0, stream, dom, b2, out);
}